// Round 15
// baseline (551.898 us; speedup 1.0000x reference)
//
#include <hip/hip_runtime.h>

#define LRC 0.01f
#define LSEQ 4096
#define HIDDIM 128

typedef float f32x2 __attribute__((ext_vector_type(2)));
typedef unsigned int u32x2 __attribute__((ext_vector_type(2)));

#define RL(x, L) __int_as_float(__builtin_amdgcn_readlane(__float_as_int(x), (L)))
#define RORADD(x, ctrl)                                                      \
  x += __int_as_float(__builtin_amdgcn_update_dpp(                           \
      0, __float_as_int(x), (ctrl), 0xf, 0xf, true))

// (validated R5..R13) 4 concurrent 64-lane sums, row-mapped outputs:
// row g holds sum of x_{sig(g)}, sig=[0,2,1,3]. Rowlead write at
// sm[base+sig] lands value c at sm[base+c].
__device__ __forceinline__ float allred4(float x0, float x1, float x2,
                                         float x3) {
  u32x2 s1 = __builtin_amdgcn_permlane32_swap(__float_as_uint(x0),
                                              __float_as_uint(x1), false, false);
  float z01 = __uint_as_float(s1.x) + __uint_as_float(s1.y);
  u32x2 s2 = __builtin_amdgcn_permlane32_swap(__float_as_uint(x2),
                                              __float_as_uint(x3), false, false);
  float z23 = __uint_as_float(s2.x) + __uint_as_float(s2.y);
  u32x2 s3 = __builtin_amdgcn_permlane16_swap(__float_as_uint(z01),
                                              __float_as_uint(z23), false, false);
  float y = __uint_as_float(s3.x) + __uint_as_float(s3.y);
  RORADD(y, 0x128); RORADD(y, 0x124); RORADD(y, 0x122); RORADD(y, 0x121);
  return y;
}

// Barrier WITHOUT vmcnt drain: global prefetches stay in flight.
#define BAR() asm volatile("s_waitcnt lgkmcnt(0)\n\ts_barrier" ::: "memory")

__device__ __forceinline__ float dot2(f32x2 a, f32x2 b) {
  return fmaf(a.x, b.x, a.y * b.y);
}

// E=4 epochs. Double-buffered LDS, buffer ep at ep*96 floats:
//   TP[4][8] at +0 | KK at +32 (step jj block at +32+8jj, terms t=0..jj+3,
//   term t is da(4e-4+t)) | DA[4][8] at +64.
// A epoch e: reads TP/KK[e&1] (B wrote in e-1), writes DA[e&1].
// B epoch f: reads DA[(f+1)&1] (=(f-1)&1, A wrote in f-1), applies da's,
//   writes TP/KK[(f+1)&1] for A's epoch f+1. One barrier per epoch.
__global__ __launch_bounds__(128) void ttt_kernel(
    const float* __restrict__ h, const float* __restrict__ W1,
    const float* __restrict__ b1, const float* __restrict__ W2,
    const float* __restrict__ b2, float* __restrict__ out) {
  __shared__ __align__(16) float sm[192];
  const int b = blockIdx.x;
  const int tid = threadIdx.x;
  const int wv = tid >> 6;
  const int lane = tid & 63;
  const int g = lane >> 4;
  const int sig = ((g & 1) << 1) | (g >> 1);
  const int d0 = lane * 2;
  const bool rowlead = ((lane & 15) == 0);
  const float* __restrict__ hb = h + (size_t)b * (LSEQ * HIDDIM);

  if (wv == 0) {
    // ======================= WAVE A (serial core) =======================
    const float cneg = -(LRC * 2.0f / (float)HIDDIM);
    f32x2 w2v[8];
#pragma unroll
    for (int i = 0; i < 8; ++i) {
      w2v[i].x = W2[(size_t)d0 * 8 + i];
      w2v[i].y = W2[(size_t)(d0 + 1) * 8 + i];
    }
    f32x2 b2v = *(const f32x2*)(b2 + d0);
    float b1A = b1[sig], b1B = b1[4 + sig];
    // v(j) = row 2j+1; 8 live slots = 2 epochs
    f32x2 vS[8];
#pragma unroll
    for (int x = 0; x < 8; ++x)
      vS[x] = *(const f32x2*)(hb + (size_t)(2 * x + 1) * HIDDIM + d0);
    float pGlx = 0.0f, pGly = 0.0f;
    float pR0 = 0, pR1 = 0, pR2 = 0, pR3 = 0, pR4 = 0, pR5 = 0, pR6 = 0,
          pR7 = 0;
    float dP0A = 0, dP1A = 0, dP2A = 0, dP3A = 0;
    float dP0B = 0, dP1B = 0, dP2B = 0, dP3B = 0;

    auto CORE = [&](float aA, float aB, f32x2 vcur, float& daAo, float& daBo,
                    bool defer) {
      float rA = fmaxf(aA, 0.0f), rB = fmaxf(aB, 0.0f);
      float r0 = RL(rA, 0), r1 = RL(rA, 32), r2 = RL(rA, 16), r3 = RL(rA, 48);
      float r4 = RL(rB, 0), r5 = RL(rB, 32), r6 = RL(rB, 16), r7 = RL(rB, 48);
      float px0 = fmaf(w2v[0].x, r0, b2v.x), py0 = fmaf(w2v[0].y, r0, b2v.y);
      float px1 = w2v[1].x * r1, py1 = w2v[1].y * r1;
      px0 = fmaf(w2v[2].x, r2, px0); py0 = fmaf(w2v[2].y, r2, py0);
      px1 = fmaf(w2v[3].x, r3, px1); py1 = fmaf(w2v[3].y, r3, py1);
      px0 = fmaf(w2v[4].x, r4, px0); py0 = fmaf(w2v[4].y, r4, py0);
      px1 = fmaf(w2v[5].x, r5, px1); py1 = fmaf(w2v[5].y, r5, py1);
      px0 = fmaf(w2v[6].x, r6, px0); py0 = fmaf(w2v[6].y, r6, py0);
      px1 = fmaf(w2v[7].x, r7, px1); py1 = fmaf(w2v[7].y, r7, py1);
      float glx = (px0 + px1 - vcur.x) * cneg;
      float gly = (py0 + py1 - vcur.y) * cneg;
      float dp[8];
#pragma unroll
      for (int i = 0; i < 8; ++i) dp[i] = fmaf(w2v[i].x, glx, w2v[i].y * gly);
      float zA = allred4(dp[0], dp[1], dp[2], dp[3]);
      float zB = allred4(dp[4], dp[5], dp[6], dp[7]);
      daAo = (aA > 0.0f) ? zA : 0.0f;
      daBo = (aB > 0.0f) ? zB : 0.0f;
      if (!defer) {
        w2v[0].x = fmaf(glx, r0, w2v[0].x); w2v[0].y = fmaf(gly, r0, w2v[0].y);
        w2v[1].x = fmaf(glx, r1, w2v[1].x); w2v[1].y = fmaf(gly, r1, w2v[1].y);
        w2v[2].x = fmaf(glx, r2, w2v[2].x); w2v[2].y = fmaf(gly, r2, w2v[2].y);
        w2v[3].x = fmaf(glx, r3, w2v[3].x); w2v[3].y = fmaf(gly, r3, w2v[3].y);
        w2v[4].x = fmaf(glx, r4, w2v[4].x); w2v[4].y = fmaf(gly, r4, w2v[4].y);
        w2v[5].x = fmaf(glx, r5, w2v[5].x); w2v[5].y = fmaf(gly, r5, w2v[5].y);
        w2v[6].x = fmaf(glx, r6, w2v[6].x); w2v[6].y = fmaf(gly, r6, w2v[6].y);
        w2v[7].x = fmaf(glx, r7, w2v[7].x); w2v[7].y = fmaf(gly, r7, w2v[7].y);
        b2v.x += glx;
        b2v.y += gly;
      } else {
        pGlx = glx; pGly = gly;
        pR0 = r0; pR1 = r1; pR2 = r2; pR3 = r3;
        pR4 = r4; pR5 = r5; pR6 = r6; pR7 = r7;
      }
    };
    auto APPLY_PEND = [&]() {
      w2v[0].x = fmaf(pGlx, pR0, w2v[0].x); w2v[0].y = fmaf(pGly, pR0, w2v[0].y);
      w2v[1].x = fmaf(pGlx, pR1, w2v[1].x); w2v[1].y = fmaf(pGly, pR1, w2v[1].y);
      w2v[2].x = fmaf(pGlx, pR2, w2v[2].x); w2v[2].y = fmaf(pGly, pR2, w2v[2].y);
      w2v[3].x = fmaf(pGlx, pR3, w2v[3].x); w2v[3].y = fmaf(pGly, pR3, w2v[3].y);
      w2v[4].x = fmaf(pGlx, pR4, w2v[4].x); w2v[4].y = fmaf(pGly, pR4, w2v[4].y);
      w2v[5].x = fmaf(pGlx, pR5, w2v[5].x); w2v[5].y = fmaf(pGly, pR5, w2v[5].y);
      w2v[6].x = fmaf(pGlx, pR6, w2v[6].x); w2v[6].y = fmaf(pGly, pR6, w2v[6].y);
      w2v[7].x = fmaf(pGlx, pR7, w2v[7].x); w2v[7].y = fmaf(pGly, pR7, w2v[7].y);
      b2v.x += pGlx;
      b2v.y += pGly;
    };

    BAR();  // init: B wrote buffer 0

    for (int e = 0; e < 511; ++e) {
      const int bb = (e & 1) * 96;
      float tp0A = sm[bb + sig],      tp0B = sm[bb + 4 + sig];
      float4 c0 = *(float4*)&sm[bb + 32];
      float tp1A = sm[bb + 8 + sig],  tp1B = sm[bb + 12 + sig];
      float4 c1 = *(float4*)&sm[bb + 40];
      float  c1e = sm[bb + 44];
      float tp2A = sm[bb + 16 + sig], tp2B = sm[bb + 20 + sig];
      float4 c2 = *(float4*)&sm[bb + 48];
      float2 c2e = *(float2*)&sm[bb + 52];
      float tp3A = sm[bb + 24 + sig], tp3B = sm[bb + 28 + sig];
      float4 c3 = *(float4*)&sm[bb + 56];
      float2 c3e = *(float2*)&sm[bb + 60];
      float  c3f = sm[bb + 62];
      // v prefetch for epoch e+2: v(4e+8..4e+11)
      int rv0 = 8 * e + 17; if (rv0 > 4095) rv0 = 4095;
      int rv1 = 8 * e + 19; if (rv1 > 4095) rv1 = 4095;
      int rv2 = 8 * e + 21; if (rv2 > 4095) rv2 = 4095;
      int rv3 = 8 * e + 23; if (rv3 > 4095) rv3 = 4095;
      f32x2 vI0 = *(const f32x2*)(hb + (size_t)rv0 * HIDDIM + d0);
      f32x2 vI1 = *(const f32x2*)(hb + (size_t)rv1 * HIDDIM + d0);
      f32x2 vI2 = *(const f32x2*)(hb + (size_t)rv2 * HIDDIM + d0);
      f32x2 vI3 = *(const f32x2*)(hb + (size_t)rv3 * HIDDIM + d0);
      APPLY_PEND();  // prev epoch's deferred W2/b2; shadows the LDS reads
      // jj=0 (j=4e)
      float a0A = fmaf(dP0A, c0.x, fmaf(dP1A, c0.y,
                  fmaf(dP2A, c0.z, fmaf(dP3A, c0.w, tp0A + b1A))));
      float a0B = fmaf(dP0B, c0.x, fmaf(dP1B, c0.y,
                  fmaf(dP2B, c0.z, fmaf(dP3B, c0.w, tp0B + b1B))));
      float da0A, da0B;
      CORE(a0A, a0B, vS[0], da0A, da0B, false);
      if (rowlead) { sm[bb + 64 + sig] = da0A; sm[bb + 68 + sig] = da0B; }
      b1A += da0A; b1B += da0B;
      // jj=1
      float a1A = fmaf(dP0A, c1.x, fmaf(dP1A, c1.y, fmaf(dP2A, c1.z,
                  fmaf(dP3A, c1.w, fmaf(da0A, c1e, tp1A + b1A)))));
      float a1B = fmaf(dP0B, c1.x, fmaf(dP1B, c1.y, fmaf(dP2B, c1.z,
                  fmaf(dP3B, c1.w, fmaf(da0B, c1e, tp1B + b1B)))));
      float da1A, da1B;
      CORE(a1A, a1B, vS[1], da1A, da1B, false);
      if (rowlead) { sm[bb + 72 + sig] = da1A; sm[bb + 76 + sig] = da1B; }
      b1A += da1A; b1B += da1B;
      // jj=2
      float a2A = fmaf(dP0A, c2.x, fmaf(dP1A, c2.y, fmaf(dP2A, c2.z,
                  fmaf(dP3A, c2.w, fmaf(da0A, c2e.x,
                  fmaf(da1A, c2e.y, tp2A + b1A))))));
      float a2B = fmaf(dP0B, c2.x, fmaf(dP1B, c2.y, fmaf(dP2B, c2.z,
                  fmaf(dP3B, c2.w, fmaf(da0B, c2e.x,
                  fmaf(da1B, c2e.y, tp2B + b1B))))));
      float da2A, da2B;
      CORE(a2A, a2B, vS[2], da2A, da2B, false);
      if (rowlead) { sm[bb + 80 + sig] = da2A; sm[bb + 84 + sig] = da2B; }
      b1A += da2A; b1B += da2B;
      // jj=3 (defer W2/b2 update across the barrier)
      float a3A = fmaf(dP0A, c3.x, fmaf(dP1A, c3.y, fmaf(dP2A, c3.z,
                  fmaf(dP3A, c3.w, fmaf(da0A, c3e.x, fmaf(da1A, c3e.y,
                  fmaf(da2A, c3f, tp3A + b1A)))))));
      float a3B = fmaf(dP0B, c3.x, fmaf(dP1B, c3.y, fmaf(dP2B, c3.z,
                  fmaf(dP3B, c3.w, fmaf(da0B, c3e.x, fmaf(da1B, c3e.y,
                  fmaf(da2B, c3f, tp3B + b1B)))))));
      float da3A, da3B;
      CORE(a3A, a3B, vS[3], da3A, da3B, true);
      if (rowlead) { sm[bb + 88 + sig] = da3A; sm[bb + 92 + sig] = da3B; }
      b1A += da3A; b1B += da3B;
      dP0A = da0A; dP1A = da1A; dP2A = da2A; dP3A = da3A;
      dP0B = da0B; dP1B = da1B; dP2B = da2B; dP3B = da3B;
      vS[0] = vS[4]; vS[1] = vS[5]; vS[2] = vS[6]; vS[3] = vS[7];
      vS[4] = vI0; vS[5] = vI1; vS[6] = vI2; vS[7] = vI3;
      BAR();
    }
    // ---- tail epoch e=511 (buffer 1): steps 2044..2046 + final predict ----
    {
      const int bb = 96;
      float tp0A = sm[bb + sig],      tp0B = sm[bb + 4 + sig];
      float4 c0 = *(float4*)&sm[bb + 32];
      float tp1A = sm[bb + 8 + sig],  tp1B = sm[bb + 12 + sig];
      float4 c1 = *(float4*)&sm[bb + 40];
      float  c1e = sm[bb + 44];
      float tp2A = sm[bb + 16 + sig], tp2B = sm[bb + 20 + sig];
      float4 c2 = *(float4*)&sm[bb + 48];
      float2 c2e = *(float2*)&sm[bb + 52];
      float tp3A = sm[bb + 24 + sig], tp3B = sm[bb + 28 + sig];
      float4 c3 = *(float4*)&sm[bb + 56];
      float2 c3e = *(float2*)&sm[bb + 60];
      float  c3f = sm[bb + 62];
      APPLY_PEND();
      float a0A = fmaf(dP0A, c0.x, fmaf(dP1A, c0.y,
                  fmaf(dP2A, c0.z, fmaf(dP3A, c0.w, tp0A + b1A))));
      float a0B = fmaf(dP0B, c0.x, fmaf(dP1B, c0.y,
                  fmaf(dP2B, c0.z, fmaf(dP3B, c0.w, tp0B + b1B))));
      float da0A, da0B;
      CORE(a0A, a0B, vS[0], da0A, da0B, false);  // step 2044
      b1A += da0A; b1B += da0B;
      float a1A = fmaf(dP0A, c1.x, fmaf(dP1A, c1.y, fmaf(dP2A, c1.z,
                  fmaf(dP3A, c1.w, fmaf(da0A, c1e, tp1A + b1A)))));
      float a1B = fmaf(dP0B, c1.x, fmaf(dP1B, c1.y, fmaf(dP2B, c1.z,
                  fmaf(dP3B, c1.w, fmaf(da0B, c1e, tp1B + b1B)))));
      float da1A, da1B;
      CORE(a1A, a1B, vS[1], da1A, da1B, false);  // step 2045
      b1A += da1A; b1B += da1B;
      float a2A = fmaf(dP0A, c2.x, fmaf(dP1A, c2.y, fmaf(dP2A, c2.z,
                  fmaf(dP3A, c2.w, fmaf(da0A, c2e.x,
                  fmaf(da1A, c2e.y, tp2A + b1A))))));
      float a2B = fmaf(dP0B, c2.x, fmaf(dP1B, c2.y, fmaf(dP2B, c2.z,
                  fmaf(dP3B, c2.w, fmaf(da0B, c2e.x,
                  fmaf(da1B, c2e.y, tp2B + b1B))))));
      float da2A, da2B;
      CORE(a2A, a2B, vS[2], da2A, da2B, false);  // step 2046
      b1A += da2A; b1B += da2B;
      // a(2047) = W1_fin·x + b1_fin  (x fed through as k(2047))
      float fA = fmaf(dP0A, c3.x, fmaf(dP1A, c3.y, fmaf(dP2A, c3.z,
                 fmaf(dP3A, c3.w, fmaf(da0A, c3e.x, fmaf(da1A, c3e.y,
                 fmaf(da2A, c3f, tp3A + b1A)))))));
      float fB = fmaf(dP0B, c3.x, fmaf(dP1B, c3.y, fmaf(dP2B, c3.z,
                 fmaf(dP3B, c3.w, fmaf(da0B, c3e.x, fmaf(da1B, c3e.y,
                 fmaf(da2B, c3f, tp3B + b1B)))))));
      float rA = fmaxf(fA, 0.0f), rB = fmaxf(fB, 0.0f);
      float r0 = RL(rA, 0), r1 = RL(rA, 32), r2 = RL(rA, 16), r3 = RL(rA, 48);
      float r4 = RL(rB, 0), r5 = RL(rB, 32), r6 = RL(rB, 16), r7 = RL(rB, 48);
      float ox = fmaf(w2v[0].x, r0, b2v.x), oy = fmaf(w2v[0].y, r0, b2v.y);
      ox = fmaf(w2v[1].x, r1, ox); oy = fmaf(w2v[1].y, r1, oy);
      ox = fmaf(w2v[2].x, r2, ox); oy = fmaf(w2v[2].y, r2, oy);
      ox = fmaf(w2v[3].x, r3, ox); oy = fmaf(w2v[3].y, r3, oy);
      ox = fmaf(w2v[4].x, r4, ox); oy = fmaf(w2v[4].y, r4, oy);
      ox = fmaf(w2v[5].x, r5, ox); oy = fmaf(w2v[5].y, r5, oy);
      ox = fmaf(w2v[6].x, r6, ox); oy = fmaf(w2v[6].y, r6, oy);
      ox = fmaf(w2v[7].x, r7, ox); oy = fmaf(w2v[7].y, r7, oy);
      f32x2 o = {ox, oy};
      *(f32x2*)(out + (size_t)b * HIDDIM + d0) = o;
    }
  } else {
    // ======================= WAVE B (W1 owner) =======================
    f32x2 w1v[8];
#pragma unroll
    for (int i = 0; i < 8; ++i)
      w1v[i] = *(const f32x2*)(W1 + i * HIDDIM + d0);
    // kW[i] = k(4f-4+i); k(m) row = (m>=2047) ? 4095 : 2m
    f32x2 kW[16];
#pragma unroll
    for (int x = 0; x < 4; ++x) {
      kW[4 + x] = *(const f32x2*)(hb + (size_t)(2 * x) * HIDDIM + d0);       // k(0..3)
      kW[8 + x] = *(const f32x2*)(hb + (size_t)(8 + 2 * x) * HIDDIM + d0);   // k(4..7)
      kW[12 + x] = *(const f32x2*)(hb + (size_t)(16 + 2 * x) * HIDDIM + d0); // k(8..11)
    }
    kW[0] = kW[4]; kW[1] = kW[4]; kW[2] = kW[4]; kW[3] = kW[4];  // dummies
    // zero buffer0 KK block and buffer1 DA block (avoid 0*garbage = NaN)
    if (lane < 32) { sm[32 + lane] = 0.0f; sm[96 + 64 + lane] = 0.0f; }
    // init buffer 0: TP(0..3) with W1init; within-epoch kk at t>=4 slots
    {
      float tp[8];
#pragma unroll
      for (int i = 0; i < 8; ++i) tp[i] = dot2(w1v[i], kW[4]);
      float t0A = allred4(tp[0], tp[1], tp[2], tp[3]);
      float t0B = allred4(tp[4], tp[5], tp[6], tp[7]);
#pragma unroll
      for (int i = 0; i < 8; ++i) tp[i] = dot2(w1v[i], kW[5]);
      float t1A = allred4(tp[0], tp[1], tp[2], tp[3]);
      float t1B = allred4(tp[4], tp[5], tp[6], tp[7]);
#pragma unroll
      for (int i = 0; i < 8; ++i) tp[i] = dot2(w1v[i], kW[6]);
      float t2A = allred4(tp[0], tp[1], tp[2], tp[3]);
      float t2B = allred4(tp[4], tp[5], tp[6], tp[7]);
#pragma unroll
      for (int i = 0; i < 8; ++i) tp[i] = dot2(w1v[i], kW[7]);
      float t3A = allred4(tp[0], tp[1], tp[2], tp[3]);
      float t3B = allred4(tp[4], tp[5], tp[6], tp[7]);
      float y3 = allred4(dot2(kW[4], kW[5]), 0.0f, 0.0f, 0.0f);
      float y5 = allred4(dot2(kW[4], kW[6]), dot2(kW[5], kW[6]), 0.0f, 0.0f);
      float y7 = allred4(dot2(kW[4], kW[7]), dot2(kW[5], kW[7]),
                         dot2(kW[6], kW[7]), 0.0f);
      if (rowlead) {
        sm[0 + sig] = t0A;  sm[4 + sig] = t0B;
        sm[8 + sig] = t1A;  sm[12 + sig] = t1B;
        sm[16 + sig] = t2A; sm[20 + sig] = t2B;
        sm[24 + sig] = t3A; sm[28 + sig] = t3B;
        sm[44 + sig] = y3;  sm[52 + sig] = y5;  sm[60 + sig] = y7;
      }
    }
    BAR();  // init

    for (int f = 0; f < 511; ++f) {
      const int bb = ((f + 1) & 1) * 96;
      // da(4(f-1)..4(f-1)+3), written by A one barrier ago
      float4 q0 = *(float4*)&sm[bb + 64], q1 = *(float4*)&sm[bb + 68];
      float4 q2 = *(float4*)&sm[bb + 72], q3 = *(float4*)&sm[bb + 76];
      float4 q4 = *(float4*)&sm[bb + 80], q5 = *(float4*)&sm[bb + 84];
      float4 q6 = *(float4*)&sm[bb + 88], q7 = *(float4*)&sm[bb + 92];
      // prefetch k(4f+12..4f+15) (used as kW[8..11] two epochs on)
      int m0 = 4 * f + 12;
      int rr0 = (m0 + 0 >= 2047) ? 4095 : 2 * (m0 + 0);
      int rr1 = (m0 + 1 >= 2047) ? 4095 : 2 * (m0 + 1);
      int rr2 = (m0 + 2 >= 2047) ? 4095 : 2 * (m0 + 2);
      int rr3 = (m0 + 3 >= 2047) ? 4095 : 2 * (m0 + 3);
      f32x2 kN0 = *(const f32x2*)(hb + (size_t)rr0 * HIDDIM + d0);
      f32x2 kN1 = *(const f32x2*)(hb + (size_t)rr1 * HIDDIM + d0);
      f32x2 kN2 = *(const f32x2*)(hb + (size_t)rr2 * HIDDIM + d0);
      f32x2 kN3 = *(const f32x2*)(hb + (size_t)rr3 * HIDDIM + d0);
      // kk partials + reduces (k-only; fills the DA-read shadow)
      float yq0 = allred4(dot2(kW[4], kW[8]), dot2(kW[5], kW[8]),
                          dot2(kW[6], kW[8]), dot2(kW[7], kW[8]));
      float yq2 = allred4(dot2(kW[4], kW[9]), dot2(kW[5], kW[9]),
                          dot2(kW[6], kW[9]), dot2(kW[7], kW[9]));
      float yq3 = allred4(dot2(kW[8], kW[9]), 0.0f, 0.0f, 0.0f);
      float yq4 = allred4(dot2(kW[4], kW[10]), dot2(kW[5], kW[10]),
                          dot2(kW[6], kW[10]), dot2(kW[7], kW[10]));
      float yq5 = allred4(dot2(kW[8], kW[10]), dot2(kW[9], kW[10]), 0.0f, 0.0f);
      float yq6 = allred4(dot2(kW[4], kW[11]), dot2(kW[5], kW[11]),
                          dot2(kW[6], kW[11]), dot2(kW[7], kW[11]));
      float yq7 = allred4(dot2(kW[8], kW[11]), dot2(kW[9], kW[11]),
                          dot2(kW[10], kW[11]), 0.0f);
      if (rowlead) {
        sm[bb + 32 + sig] = yq0;
        sm[bb + 40 + sig] = yq2;
        sm[bb + 44 + sig] = yq3;
        sm[bb + 48 + sig] = yq4;
        sm[bb + 52 + sig] = yq5;
        sm[bb + 56 + sig] = yq6;
        sm[bb + 60 + sig] = yq7;
      }
      // apply 4 rank-1 updates: W1 += da(t) x k(4(f-1)+t) = kW[t]
      float dT0[8] = {q0.x, q0.y, q0.z, q0.w, q1.x, q1.y, q1.z, q1.w};
      float dT1[8] = {q2.x, q2.y, q2.z, q2.w, q3.x, q3.y, q3.z, q3.w};
      float dT2[8] = {q4.x, q4.y, q4.z, q4.w, q5.x, q5.y, q5.z, q5.w};
      float dT3[8] = {q6.x, q6.y, q6.z, q6.w, q7.x, q7.y, q7.z, q7.w};
#pragma unroll
      for (int i = 0; i < 8; ++i) {
        w1v[i].x = fmaf(dT0[i], kW[0].x, w1v[i].x);
        w1v[i].y = fmaf(dT0[i], kW[0].y, w1v[i].y);
        w1v[i].x = fmaf(dT1[i], kW[1].x, w1v[i].x);
        w1v[i].y = fmaf(dT1[i], kW[1].y, w1v[i].y);
        w1v[i].x = fmaf(dT2[i], kW[2].x, w1v[i].x);
        w1v[i].y = fmaf(dT2[i], kW[2].y, w1v[i].y);
        w1v[i].x = fmaf(dT3[i], kW[3].x, w1v[i].x);
        w1v[i].y = fmaf(dT3[i], kW[3].y, w1v[i].y);
      }
      // TP(4f+4..4f+7) with W[4f-1]
      float tp[8];
#pragma unroll
      for (int i = 0; i < 8; ++i) tp[i] = dot2(w1v[i], kW[8]);
      float t0A = allred4(tp[0], tp[1], tp[2], tp[3]);
      float t0B = allred4(tp[4], tp[5], tp[6], tp[7]);
#pragma unroll
      for (int i = 0; i < 8; ++i) tp[i] = dot2(w1v[i], kW[9]);
      float t1A = allred4(tp[0], tp[1], tp[2], tp[3]);
      float t1B = allred4(tp[4], tp[5], tp[6], tp[7]);
#pragma unroll
      for (int i = 0; i < 8; ++i) tp[i] = dot2(w1v[i], kW[10]);
      float t2A = allred4(tp[0], tp[1], tp[2], tp[3]);
      float t2B = allred4(tp[4], tp[5], tp[6], tp[7]);
#pragma unroll
      for (int i = 0; i < 8; ++i) tp[i] = dot2(w1v[i], kW[11]);
      float t3A = allred4(tp[0], tp[1], tp[2], tp[3]);
      float t3B = allred4(tp[4], tp[5], tp[6], tp[7]);
      if (rowlead) {
        sm[bb + 0 + sig] = t0A;  sm[bb + 4 + sig] = t0B;
        sm[bb + 8 + sig] = t1A;  sm[bb + 12 + sig] = t1B;
        sm[bb + 16 + sig] = t2A; sm[bb + 20 + sig] = t2B;
        sm[bb + 24 + sig] = t3A; sm[bb + 28 + sig] = t3B;
      }
      // rotate window
#pragma unroll
      for (int i = 0; i < 12; ++i) kW[i] = kW[i + 4];
      kW[12] = kN0; kW[13] = kN1; kW[14] = kN2; kW[15] = kN3;
      BAR();
    }
  }
}

extern "C" void kernel_launch(void* const* d_in, const int* in_sizes, int n_in,
                              void* d_out, int out_size, void* d_ws, size_t ws_size,
                              hipStream_t stream) {
  const float* h  = (const float*)d_in[0];
  const float* W1 = (const float*)d_in[1];
  const float* b1 = (const float*)d_in[2];
  const float* W2 = (const float*)d_in[3];
  const float* b2 = (const float*)d_in[4];
  float* out = (float*)d_out;
  ttt_kernel<<<256, 128, 0, stream>>>(h, W1, b1, W2, b2, out);
}